// Round 1
// 623.205 us; speedup vs baseline: 1.1804x; 1.1804x over previous
//
#include <hip/hip_runtime.h>
#include <cmath>

#define EMB_V 100000
#define BATCH 256
#define SUBS  10
#define BC    2560
#define TC    20
#define TS    50

using bf16x8 = __attribute__((ext_vector_type(8))) short;
using f32x4  = __attribute__((ext_vector_type(4))) float;

__device__ __forceinline__ float sigmoidf_(float x) { return 1.f / (1.f + __expf(-x)); }

__device__ __forceinline__ unsigned short f2bf(float f) {
    unsigned int u = __float_as_uint(f);
    u += 0x7fff + ((u >> 16) & 1);   // RNE
    return (unsigned short)(u >> 16);
}
__device__ __forceinline__ float bf2f(unsigned short u) {
    return __uint_as_float(((unsigned int)u) << 16);
}

// out[c*rows + r] = in[r*cols + c]  (for fc_W -> fcWT)
__global__ void transpose_rm(const float* __restrict__ in, float* __restrict__ out,
                             int rows, int cols) {
    int o = blockIdx.x * 256 + threadIdx.x;
    if (o >= rows * cols) return;
    int c = o / rows;
    int r = o - c * rows;
    out[o] = in[r * cols + c];
}

// Pack Whh [768][256] fp32 into MFMA B-fragment-contiguous bf16 layout,
// GATE-TRIPLE-INTERLEAVED: tile ntg = cg*3 + g covers output columns that are
// gate g of h-columns cg*16..cg*16+15. Original Whh row = g*256 + cg*16 + (l&15).
// frag fi = ntg*8+kc; lane l holds k = kc*32+(l>>4)*8+j, j=0..7. dst[fi*64+l][8].
__global__ void pack_whh(const float* __restrict__ W, unsigned short* __restrict__ P) {
    int t = blockIdx.x * 256 + threadIdx.x;
    if (t >= 48 * 8 * 64) return;
    int l = t & 63, kc = (t >> 6) & 7, nt = t >> 9;
    int g = nt % 3, cg = nt / 3;
    int n = g * 256 + cg * 16 + (l & 15);
    int k = kc * 32 + (l >> 4) * 8;
    const float* src = W + n * 256 + k;
    unsigned short* dst = P + (size_t)t * 8;
#pragma unroll
    for (int j = 0; j < 8; ++j) dst[j] = f2bf(src[j]);
}

// Generic C[m][n] = sum_k A[m][k]*B[n][k], K=256 fixed, BM=BN=128.
template <bool GATHER, bool OBF16, bool NGUARD>
__global__ __launch_bounds__(256, 2) void gemm_abt(
    const float* __restrict__ A, const int* __restrict__ tok,
    const float* __restrict__ B, void* __restrict__ Cout,
    int N, int ldc)
{
    __shared__ unsigned short Asub[128][72];
    __shared__ unsigned short Bsub[128][72];
    const int tid = threadIdx.x;
    const int l = tid & 63, wave = tid >> 6;
    const int lm = l & 15, quad = l >> 4;
    const int wm = wave >> 1, wn = wave & 1;
    const int n0 = blockIdx.x * 128, m0 = blockIdx.y * 128;

    f32x4 acc[4][4];
#pragma unroll
    for (int mi = 0; mi < 4; ++mi)
#pragma unroll
        for (int ni = 0; ni < 4; ++ni) acc[mi][ni] = (f32x4){0.f, 0.f, 0.f, 0.f};

    for (int kk = 0; kk < 4; ++kk) {
        const int k0 = kk * 64;
#pragma unroll
        for (int i = 0; i < 8; ++i) {
            int slot = tid + i * 256;
            int row = slot >> 4, c4 = (slot & 15) * 4;
            const float* src = GATHER
                ? A + (size_t)tok[m0 + row] * 256 + k0 + c4
                : A + (size_t)(m0 + row) * 256 + k0 + c4;
            float4 v = *(const float4*)src;
            *(ushort4*)&Asub[row][c4] = make_ushort4(f2bf(v.x), f2bf(v.y), f2bf(v.z), f2bf(v.w));
        }
#pragma unroll
        for (int i = 0; i < 8; ++i) {
            int slot = tid + i * 256;
            int row = slot >> 4, c4 = (slot & 15) * 4;
            int n = n0 + row;
            float4 v;
            if (!NGUARD || n < N) v = *(const float4*)(B + (size_t)n * 256 + k0 + c4);
            else                  v = make_float4(0.f, 0.f, 0.f, 0.f);
            *(ushort4*)&Bsub[row][c4] = make_ushort4(f2bf(v.x), f2bf(v.y), f2bf(v.z), f2bf(v.w));
        }
        __syncthreads();
#pragma unroll
        for (int kc = 0; kc < 2; ++kc) {
            bf16x8 af[4], bfv[4];
#pragma unroll
            for (int mi = 0; mi < 4; ++mi)
                af[mi] = *(const bf16x8*)&Asub[wm * 64 + mi * 16 + lm][kc * 32 + quad * 8];
#pragma unroll
            for (int ni = 0; ni < 4; ++ni)
                bfv[ni] = *(const bf16x8*)&Bsub[wn * 64 + ni * 16 + lm][kc * 32 + quad * 8];
#pragma unroll
            for (int mi = 0; mi < 4; ++mi)
#pragma unroll
                for (int ni = 0; ni < 4; ++ni)
                    acc[mi][ni] = __builtin_amdgcn_mfma_f32_16x16x32_bf16(
                        af[mi], bfv[ni], acc[mi][ni], 0, 0, 0);
        }
        __syncthreads();
    }
#pragma unroll
    for (int mi = 0; mi < 4; ++mi)
#pragma unroll
        for (int ni = 0; ni < 4; ++ni) {
            int col = n0 + wn * 64 + ni * 16 + lm;
            if (NGUARD && col >= N) continue;
#pragma unroll
            for (int i = 0; i < 4; ++i) {
                int row = m0 + wm * 64 + mi * 16 + quad * 4 + i;
                if (OBF16)
                    ((unsigned short*)Cout)[(size_t)row * ldc + col] = f2bf(acc[mi][ni][i]);
                else
                    ((float*)Cout)[(size_t)row * ldc + col] = acc[mi][ni][i];
            }
        }
}

// Fused GRU scans (cat: blocks 0..159, T=20; short: blocks 160..175, T=50).
// 512 threads = 8 waves; 16 rows/block. Whh resident: 30 B-frags/wave in VGPRs,
// 18 B-frags/wave in LDS (staged once). Gate-triple-interleaved packing means
// each wave's accumulators hold (r,z,n) for its own 32 h-columns -> gates are
// computed in-lane, no gh LDS round trip. h kept bf16 in LDS (for A-frags) and
// fp32 in registers (for the z*h_old term). Raw s_barrier (no vmcnt drain) so
// the per-step gi prefetch stays in flight across the MFMA phase.
__global__ __launch_bounds__(512, 2) void gru_scan_fused(
    const unsigned short* __restrict__ gi_c, const unsigned short* __restrict__ pW_c,
    const float* __restrict__ bih_c, const float* __restrict__ bhh_c,
    const int* __restrict__ len_c, const float* __restrict__ mask_c,
    float* __restrict__ out_c,
    const unsigned short* __restrict__ gi_s, const unsigned short* __restrict__ pW_s,
    const float* __restrict__ bih_s, const float* __restrict__ bhh_s,
    const int* __restrict__ len_s, const float* __restrict__ mask_s,
    float* __restrict__ out_s)
{
    __shared__ unsigned short h_lds[16][264];              // 8448 B, 16B-aligned rows
    __shared__ unsigned short b_lds[8 * 18 * 64 * 8];      // 147456 B

    const bool is_cat = blockIdx.x < (BC / 16);
    const int  T      = is_cat ? TC : TS;
    const int  row0   = (is_cat ? blockIdx.x : blockIdx.x - BC / 16) * 16;
    const unsigned short* gi   = is_cat ? gi_c  : gi_s;
    const unsigned short* pW   = is_cat ? pW_c  : pW_s;
    const float*          bih  = is_cat ? bih_c : bih_s;
    const float*          bhh  = is_cat ? bhh_c : bhh_s;
    const int*            lenp = is_cat ? len_c : len_s;
    const float*          mask = is_cat ? mask_c : mask_s;
    float*                outp = is_cat ? out_c : out_s;

    const int tid  = threadIdx.x;
    const int l    = tid & 63, w = tid >> 6;
    const int lm   = l & 15,   quad = l >> 4;

    // zero h state
    for (int i = tid; i < 16 * 264; i += 512) ((unsigned short*)h_lds)[i] = 0;

    // load 30 register B-frags (kc 0..4) and stage 18 LDS B-frags (kc 5..7)
    bf16x8 breg[6][5];
#pragma unroll
    for (int ti = 0; ti < 6; ++ti)
#pragma unroll
        for (int kc = 0; kc < 5; ++kc)
            breg[ti][kc] = *((const bf16x8*)pW + (size_t)((6 * w + ti) * 8 + kc) * 64 + l);
#pragma unroll
    for (int ti = 0; ti < 6; ++ti)
#pragma unroll
        for (int kc = 5; kc < 8; ++kc) {
            bf16x8 v = *((const bf16x8*)pW + (size_t)((6 * w + ti) * 8 + kc) * 64 + l);
            *(bf16x8*)&b_lds[((size_t)(w * 18 + ti * 3 + (kc - 5)) * 64 + l) * 8] = v;
        }

    // per-lane columns and bias constants
    const int c0 = 32 * w + lm, c1 = c0 + 16;
    const float cR0 = bih[c0] + bhh[c0],             cR1 = bih[c1] + bhh[c1];
    const float cZ0 = bih[256 + c0] + bhh[256 + c0], cZ1 = bih[256 + c1] + bhh[256 + c1];
    const float cNi0 = bih[512 + c0], cNi1 = bih[512 + c1];
    const float cNh0 = bhh[512 + c0], cNh1 = bhh[512 + c1];

    int len[4];
#pragma unroll
    for (int i = 0; i < 4; ++i) len[i] = lenp[row0 + quad * 4 + i];

    const unsigned short* gp[4];
#pragma unroll
    for (int i = 0; i < 4; ++i)
        gp[i] = gi + (size_t)(row0 + quad * 4 + i) * T * 768;

    float hold0[4] = {0.f, 0.f, 0.f, 0.f};
    float hold1[4] = {0.f, 0.f, 0.f, 0.f};

    __syncthreads();

    for (int t = 0; t < T; ++t) {
        // prefetch this step's gi (consumed at gate time; stays in flight
        // across the raw barriers — no vmcnt drain)
        unsigned short g0[4][3], g1[4][3];
#pragma unroll
        for (int i = 0; i < 4; ++i) {
            const unsigned short* p = gp[i] + (size_t)t * 768;
            g0[i][0] = p[c0];       g0[i][1] = p[256 + c0]; g0[i][2] = p[512 + c0];
            g1[i][0] = p[c1];       g1[i][1] = p[256 + c1]; g1[i][2] = p[512 + c1];
        }

        // A-frags: h rows lm, all 256 cols
        bf16x8 a[8];
#pragma unroll
        for (int kc = 0; kc < 8; ++kc)
            a[kc] = *(const bf16x8*)&h_lds[lm][kc * 32 + quad * 8];

        // barrier A: all h reads complete before anyone overwrites h
        asm volatile("s_waitcnt lgkmcnt(0)" ::: "memory");
        __builtin_amdgcn_sched_barrier(0);
        __builtin_amdgcn_s_barrier();
        __builtin_amdgcn_sched_barrier(0);

        f32x4 acc[6];
#pragma unroll
        for (int ti = 0; ti < 6; ++ti) acc[ti] = (f32x4){0.f, 0.f, 0.f, 0.f};
#pragma unroll
        for (int ti = 0; ti < 6; ++ti) {
#pragma unroll
            for (int kc = 0; kc < 5; ++kc)
                acc[ti] = __builtin_amdgcn_mfma_f32_16x16x32_bf16(
                    a[kc], breg[ti][kc], acc[ti], 0, 0, 0);
#pragma unroll
            for (int kc = 5; kc < 8; ++kc) {
                bf16x8 b = *(const bf16x8*)&b_lds[((size_t)(w * 18 + ti * 3 + (kc - 5)) * 64 + l) * 8];
                acc[ti] = __builtin_amdgcn_mfma_f32_16x16x32_bf16(
                    a[kc], b, acc[ti], 0, 0, 0);
            }
        }

        // gates in-lane: acc[0..2] = (r,z,n) for col c0; acc[3..5] for col c1
#pragma unroll
        for (int i = 0; i < 4; ++i) {
            const int r = quad * 4 + i;
            {
                float rg = sigmoidf_(bf2f(g0[i][0]) + acc[0][i] + cR0);
                float zg = sigmoidf_(bf2f(g0[i][1]) + acc[1][i] + cZ0);
                float ng = tanhf(bf2f(g0[i][2]) + cNi0 + rg * (acc[2][i] + cNh0));
                float hn = zg * (hold0[i] - ng) + ng;
                hold0[i] = hn;
                h_lds[r][c0] = f2bf(hn);
                if (t == len[i])
                    outp[(size_t)(row0 + r) * 256 + c0] = hn * mask[(row0 + r) * T + t];
            }
            {
                float rg = sigmoidf_(bf2f(g1[i][0]) + acc[3][i] + cR1);
                float zg = sigmoidf_(bf2f(g1[i][1]) + acc[4][i] + cZ1);
                float ng = tanhf(bf2f(g1[i][2]) + cNi1 + rg * (acc[5][i] + cNh1));
                float hn = zg * (hold1[i] - ng) + ng;
                hold1[i] = hn;
                h_lds[r][c1] = f2bf(hn);
                if (t == len[i])
                    outp[(size_t)(row0 + r) * 256 + c1] = hn * mask[(row0 + r) * T + t];
            }
        }

        // barrier B: h_{t+1} writes visible before next step's reads
        asm volatile("s_waitcnt lgkmcnt(0)" ::: "memory");
        __builtin_amdgcn_sched_barrier(0);
        __builtin_amdgcn_s_barrier();
        __builtin_amdgcn_sched_barrier(0);
    }
}

// Per-batch attention + fc; also writes target (as float) into d_out tail.
__global__ __launch_bounds__(256) void attn_fc(
    const float* __restrict__ seq_cate, const float* __restrict__ out_short,
    const float* __restrict__ mask_seq, const float* __restrict__ fcWT,
    const float* __restrict__ fc_b, const int* __restrict__ target,
    float* __restrict__ fc_out, float* __restrict__ d_out)
{
    __shared__ float sc[SUBS][256];
    __shared__ float os[256];
    __shared__ float part[SUBS][256];
    __shared__ float mix[512];
    const int b = blockIdx.x, tid = threadIdx.x;

    os[tid] = out_short[b * 256 + tid];
    for (int s = 0; s < SUBS; ++s) sc[s][tid] = seq_cate[(size_t)(b * SUBS + s) * 256 + tid];
    __syncthreads();

    for (int s = 0; s < SUBS; ++s) part[s][tid] = sc[s][tid] * os[tid];
    __syncthreads();
    for (int off = 128; off >= 1; off >>= 1) {
        if (tid < off)
            for (int s = 0; s < SUBS; ++s) part[s][tid] += part[s][tid + off];
        __syncthreads();
    }

    float w[SUBS];
    float m = -1e30f;
    for (int s = 0; s < SUBS; ++s) m = fmaxf(m, part[s][0]);
    float sum = 0.f;
    for (int s = 0; s < SUBS; ++s) { w[s] = __expf(part[s][0] - m); sum += w[s]; }
    float tot = 0.f;
    for (int s = 0; s < SUBS; ++s) { w[s] = (w[s] / sum) * mask_seq[b * SUBS + s]; tot += w[s]; }
    float inv = 1.f / tot;

    float sumc = 0.f;
    for (int s = 0; s < SUBS; ++s) sumc += w[s] * inv * sc[s][tid];
    mix[tid] = sumc;
    mix[256 + tid] = os[tid];
    __syncthreads();

    float acc = fc_b[tid];
    for (int jj = 0; jj < 512; ++jj) acc = fmaf(mix[jj], fcWT[jj * 256 + tid], acc);
    fc_out[b * 256 + tid] = acc;

    if (tid == 0) d_out[(size_t)BATCH * EMB_V + b] = (float)target[b];
}

extern "C" void kernel_launch(void* const* d_in, const int* in_sizes, int n_in,
                              void* d_out, int out_size, void* d_ws, size_t ws_size,
                              hipStream_t stream) {
    const int*   input_cate   = (const int*)d_in[0];
    const float* mask_cate    = (const float*)d_in[1];
    const float* mask_seq     = (const float*)d_in[2];
    const int*   subseqLen    = (const int*)d_in[5];
    const int*   input_batch  = (const int*)d_in[7];
    const float* mask_batch   = (const float*)d_in[8];
    const int*   seqLen_batch = (const int*)d_in[9];
    const int*   target       = (const int*)d_in[10];
    const float* emb          = (const float*)d_in[12];
    const float* Wih_c        = (const float*)d_in[13];
    const float* Whh_c        = (const float*)d_in[14];
    const float* bih_c        = (const float*)d_in[15];
    const float* bhh_c        = (const float*)d_in[16];
    const float* Wih_s        = (const float*)d_in[17];
    const float* Whh_s        = (const float*)d_in[18];
    const float* bih_s        = (const float*)d_in[19];
    const float* bhh_s        = (const float*)d_in[20];
    const float* fc_W         = (const float*)d_in[21];
    const float* fc_b         = (const float*)d_in[22];
    float* out = (float*)d_out;

    float* ws = (float*)d_ws;
    float* fcWT       = ws;                      // 131072 f
    float* out_short  = ws + 131072;             // 65536
    float* fc_out     = ws + 196608;             // 65536
    float* seq_cate   = ws + 262144;             // 655360
    unsigned short* packW_c = (unsigned short*)(ws + 917504);   // 98304 f
    unsigned short* packW_s = (unsigned short*)(ws + 1015808);  // 98304 f
    unsigned short* gi_c    = (unsigned short*)(ws + 1114112);  // 19660800 f
    unsigned short* gi_s    = (unsigned short*)(ws + 20774912); // 4915200 f

    transpose_rm<<<512, 256, 0, stream>>>(fc_W, fcWT, 256, 512);
    pack_whh<<<96, 256, 0, stream>>>(Whh_c, packW_c);
    pack_whh<<<96, 256, 0, stream>>>(Whh_s, packW_s);

    // input-gate GEMMs: gi = emb[tok] @ Wih^T  (bf16 out)
    gemm_abt<true, true, false><<<dim3(6, 400), 256, 0, stream>>>(
        emb, input_cate, Wih_c, gi_c, 768, 768);
    gemm_abt<true, true, false><<<dim3(6, 100), 256, 0, stream>>>(
        emb, input_batch, Wih_s, gi_s, 768, 768);

    // fused recurrent scans: 160 cat blocks + 16 short blocks, 512 thr
    gru_scan_fused<<<BC / 16 + BATCH / 16, 512, 0, stream>>>(
        gi_c, packW_c, bih_c, bhh_c, subseqLen, mask_cate, seq_cate,
        gi_s, packW_s, bih_s, bhh_s, seqLen_batch, mask_batch, out_short);

    attn_fc<<<BATCH, 256, 0, stream>>>(
        seq_cate, out_short, mask_seq, fcWT, fc_b, target, fc_out, out);

    // logits = fc_out @ emb^T  (fp32 out)
    gemm_abt<false, false, true><<<dim3(782, 2), 256, 0, stream>>>(
        fc_out, nullptr, emb, out, EMB_V, EMB_V);
}

// Round 2
// 459.660 us; speedup vs baseline: 1.6004x; 1.3558x over previous
//
#include <hip/hip_runtime.h>
#include <cmath>

#define EMB_V 100000
#define BATCH 256
#define SUBS  10
#define BC    2560
#define TC    20
#define TS    50

using bf16x8 = __attribute__((ext_vector_type(8))) short;
using f32x4  = __attribute__((ext_vector_type(4))) float;

__device__ __forceinline__ unsigned short f2bf(float f) {
    unsigned int u = __float_as_uint(f);
    u += 0x7fff + ((u >> 16) & 1);   // RNE
    return (unsigned short)(u >> 16);
}
__device__ __forceinline__ float bf2f(unsigned short u) {
    return __uint_as_float(((unsigned int)u) << 16);
}
__device__ __forceinline__ float sigmoid_fast(float x) {
    return __builtin_amdgcn_rcpf(1.f + __expf(-x));
}
__device__ __forceinline__ float tanh_fast(float x) {
    float e = __expf(2.f * x);                       // inf-safe: 1 - 2/(e+1)
    return 1.f - 2.f * __builtin_amdgcn_rcpf(e + 1.f);
}

// out[c*rows + r] = in[r*cols + c]  (for fc_W -> fcWT)
__global__ void transpose_rm(const float* __restrict__ in, float* __restrict__ out,
                             int rows, int cols) {
    int o = blockIdx.x * 256 + threadIdx.x;
    if (o >= rows * cols) return;
    int c = o / rows;
    int r = o - c * rows;
    out[o] = in[r * cols + c];
}

// fp32 -> bf16 (RNE), vectorized float4 -> ushort4, grid-strided. n4 = n/4.
__global__ void f32_to_bf16(const float* __restrict__ in, unsigned short* __restrict__ out,
                            int n4) {
    for (int i = blockIdx.x * 256 + threadIdx.x; i < n4; i += gridDim.x * 256) {
        float4 v = ((const float4*)in)[i];
        ((ushort4*)out)[i] = make_ushort4(f2bf(v.x), f2bf(v.y), f2bf(v.z), f2bf(v.w));
    }
}

// Pack Whh [768][256] fp32 into MFMA B-fragment-contiguous bf16 layout,
// GATE-TRIPLE-INTERLEAVED: tile ntg = cg*3 + g covers output columns that are
// gate g of h-columns cg*16..cg*16+15. Original Whh row = g*256 + cg*16 + (l&15).
// frag fi = ntg*8+kc; lane l holds k = kc*32+(l>>4)*8+j, j=0..7. dst[fi*64+l][8].
__global__ void pack_whh(const float* __restrict__ W, unsigned short* __restrict__ P) {
    int t = blockIdx.x * 256 + threadIdx.x;
    if (t >= 48 * 8 * 64) return;
    int l = t & 63, kc = (t >> 6) & 7, nt = t >> 9;
    int g = nt % 3, cg = nt / 3;
    int n = g * 256 + cg * 16 + (l & 15);
    int k = kc * 32 + (l >> 4) * 8;
    const float* src = W + n * 256 + k;
    unsigned short* dst = P + (size_t)t * 8;
#pragma unroll
    for (int j = 0; j < 8; ++j) dst[j] = f2bf(src[j]);
}

// Generic C[m][n] = sum_k A[m][k]*B[n][k], K=256 fixed, BM=BN=128.
// A and B are PRE-CONVERTED bf16 -> staging is pure 16B/lane copies, no cvt.
template <bool GATHER, bool OBF16, bool NGUARD>
__global__ __launch_bounds__(256, 2) void gemm_abt(
    const unsigned short* __restrict__ A, const int* __restrict__ tok,
    const unsigned short* __restrict__ B, void* __restrict__ Cout,
    int N, int ldc)
{
    __shared__ unsigned short Asub[128][72];
    __shared__ unsigned short Bsub[128][72];
    const int tid = threadIdx.x;
    const int l = tid & 63, wave = tid >> 6;
    const int lm = l & 15, quad = l >> 4;
    const int wm = wave >> 1, wn = wave & 1;
    const int n0 = blockIdx.x * 128, m0 = blockIdx.y * 128;

    f32x4 acc[4][4];
#pragma unroll
    for (int mi = 0; mi < 4; ++mi)
#pragma unroll
        for (int ni = 0; ni < 4; ++ni) acc[mi][ni] = (f32x4){0.f, 0.f, 0.f, 0.f};

    for (int kk = 0; kk < 4; ++kk) {
        const int k0 = kk * 64;
        // stage A: 128 rows x 64 cols bf16 = 1024 slots of 8 elems (16B)
#pragma unroll
        for (int i = 0; i < 4; ++i) {
            int slot = tid + i * 256;
            int row = slot >> 3, g8 = (slot & 7) * 8;
            const unsigned short* src = GATHER
                ? A + (size_t)tok[m0 + row] * 256 + k0 + g8
                : A + (size_t)(m0 + row) * 256 + k0 + g8;
            *(bf16x8*)&Asub[row][g8] = *(const bf16x8*)src;
        }
#pragma unroll
        for (int i = 0; i < 4; ++i) {
            int slot = tid + i * 256;
            int row = slot >> 3, g8 = (slot & 7) * 8;
            int n = n0 + row;
            bf16x8 v = {0, 0, 0, 0, 0, 0, 0, 0};
            if (!NGUARD || n < N) v = *(const bf16x8*)(B + (size_t)n * 256 + k0 + g8);
            *(bf16x8*)&Bsub[row][g8] = v;
        }
        __syncthreads();
#pragma unroll
        for (int kc = 0; kc < 2; ++kc) {
            bf16x8 af[4], bfv[4];
#pragma unroll
            for (int mi = 0; mi < 4; ++mi)
                af[mi] = *(const bf16x8*)&Asub[wm * 64 + mi * 16 + lm][kc * 32 + quad * 8];
#pragma unroll
            for (int ni = 0; ni < 4; ++ni)
                bfv[ni] = *(const bf16x8*)&Bsub[wn * 64 + ni * 16 + lm][kc * 32 + quad * 8];
#pragma unroll
            for (int mi = 0; mi < 4; ++mi)
#pragma unroll
                for (int ni = 0; ni < 4; ++ni)
                    acc[mi][ni] = __builtin_amdgcn_mfma_f32_16x16x32_bf16(
                        af[mi], bfv[ni], acc[mi][ni], 0, 0, 0);
        }
        __syncthreads();
    }
#pragma unroll
    for (int mi = 0; mi < 4; ++mi)
#pragma unroll
        for (int ni = 0; ni < 4; ++ni) {
            int col = n0 + wn * 64 + ni * 16 + lm;
            if (NGUARD && col >= N) continue;
#pragma unroll
            for (int i = 0; i < 4; ++i) {
                int row = m0 + wm * 64 + mi * 16 + quad * 4 + i;
                if (OBF16)
                    ((unsigned short*)Cout)[(size_t)row * ldc + col] = f2bf(acc[mi][ni][i]);
                else
                    ((float*)Cout)[(size_t)row * ldc + col] = acc[mi][ni][i];
            }
        }
}

// Fused GRU scans (cat: blocks 0..159, T=20; short: blocks 160..175, T=50).
// 512 threads = 8 waves; 16 rows/block. Per wave: 31 B-frags in regs (AGPR),
// 17 in LDS. Gate-triple-interleaved Whh -> gates in-lane from accumulators.
// h double-buffered in LDS (bf16) -> ONE raw s_barrier per step, no vmcnt
// drain (gi prefetch stays in flight across the MFMA phase). Fast tanh/sigmoid.
__global__ __launch_bounds__(512, 2) void gru_scan_fused(
    const unsigned short* __restrict__ gi_c, const unsigned short* __restrict__ pW_c,
    const float* __restrict__ bih_c, const float* __restrict__ bhh_c,
    const int* __restrict__ len_c, const float* __restrict__ mask_c,
    float* __restrict__ out_c,
    const unsigned short* __restrict__ gi_s, const unsigned short* __restrict__ pW_s,
    const float* __restrict__ bih_s, const float* __restrict__ bhh_s,
    const int* __restrict__ len_s, const float* __restrict__ mask_s,
    float* __restrict__ out_s)
{
    __shared__ unsigned short h_lds[2][16][264];   // 16896 B, double-buffered
    __shared__ unsigned short b_lds[8 * 17 * 512]; // 139264 B  (total 156160)

    const bool is_cat = blockIdx.x < (BC / 16);
    const int  T      = is_cat ? TC : TS;
    const int  row0   = (is_cat ? blockIdx.x : blockIdx.x - BC / 16) * 16;
    const unsigned short* gi   = is_cat ? gi_c  : gi_s;
    const unsigned short* pW   = is_cat ? pW_c  : pW_s;
    const float*          bih  = is_cat ? bih_c : bih_s;
    const float*          bhh  = is_cat ? bhh_c : bhh_s;
    const int*            lenp = is_cat ? len_c : len_s;
    const float*          mask = is_cat ? mask_c : mask_s;
    float*                outp = is_cat ? out_c : out_s;

    const int tid  = threadIdx.x;
    const int l    = tid & 63, w = tid >> 6;
    const int lm   = l & 15,   quad = l >> 4;

    // zero both h buffers
    for (int i = tid; i < 2 * 16 * 264; i += 512) ((unsigned short*)h_lds)[i] = 0;

    // B frags: ti==0 -> kc 0..5 in regs, kc 6..7 in LDS; ti>=1 -> kc 0..4 regs, 5..7 LDS
    bf16x8 breg[31];
#pragma unroll
    for (int ti = 0; ti < 6; ++ti)
#pragma unroll
        for (int kc = 0; kc < 8; ++kc) {
            bf16x8 v = *((const bf16x8*)pW + (size_t)((6 * w + ti) * 8 + kc) * 64 + l);
            if ((ti == 0) ? (kc < 6) : (kc < 5)) {
                breg[(ti == 0) ? kc : 6 + (ti - 1) * 5 + kc] = v;
            } else {
                int slot = (ti == 0) ? (kc - 6) : 2 + (ti - 1) * 3 + (kc - 5);
                *(bf16x8*)&b_lds[((w * 17 + slot) * 64 + l) * 8] = v;
            }
        }

    // per-lane columns and bias constants
    const int c0 = 32 * w + lm, c1 = c0 + 16;
    const float cR0 = bih[c0] + bhh[c0],             cR1 = bih[c1] + bhh[c1];
    const float cZ0 = bih[256 + c0] + bhh[256 + c0], cZ1 = bih[256 + c1] + bhh[256 + c1];
    const float cNi0 = bih[512 + c0], cNi1 = bih[512 + c1];
    const float cNh0 = bhh[512 + c0], cNh1 = bhh[512 + c1];

    int len[4];
    const unsigned short* gpa[4];
#pragma unroll
    for (int i = 0; i < 4; ++i) {
        const int r = quad * 4 + i;
        len[i] = lenp[row0 + r];
        gpa[i] = gi + (size_t)(row0 + r) * T * 768 + c0;  // pre-offset by c0
    }

    float hold0[4] = {0.f, 0.f, 0.f, 0.f};
    float hold1[4] = {0.f, 0.f, 0.f, 0.f};

    __syncthreads();

    for (int t = 0; t < T; ++t) {
        // gi prefetch: all immediate-offset loads off 4 bumped pointers
        unsigned short g00[4], g01[4], g02[4], g10[4], g11[4], g12[4];
#pragma unroll
        for (int i = 0; i < 4; ++i) {
            const unsigned short* p = gpa[i];
            g00[i] = p[0];  g01[i] = p[256]; g02[i] = p[512];
            g10[i] = p[16]; g11[i] = p[272]; g12[i] = p[528];
            gpa[i] = p + 768;
        }

        // A-frags from current h buffer
        const unsigned short (*hb)[264] = h_lds[t & 1];
        bf16x8 a[8];
#pragma unroll
        for (int kc = 0; kc < 8; ++kc)
            a[kc] = *(const bf16x8*)&hb[lm][kc * 32 + quad * 8];

        f32x4 acc[6];
#pragma unroll
        for (int ti = 0; ti < 6; ++ti) acc[ti] = (f32x4){0.f, 0.f, 0.f, 0.f};
#pragma unroll
        for (int ti = 0; ti < 6; ++ti)
#pragma unroll
            for (int kc = 0; kc < 8; ++kc) {
                bf16x8 b;
                if ((ti == 0) ? (kc < 6) : (kc < 5)) {
                    b = breg[(ti == 0) ? kc : 6 + (ti - 1) * 5 + kc];
                } else {
                    int slot = (ti == 0) ? (kc - 6) : 2 + (ti - 1) * 3 + (kc - 5);
                    b = *(const bf16x8*)&b_lds[((w * 17 + slot) * 64 + l) * 8];
                }
                acc[ti] = __builtin_amdgcn_mfma_f32_16x16x32_bf16(a[kc], b, acc[ti], 0, 0, 0);
            }

        // gates in-lane: acc[0..2] = (r,z,n) for col c0; acc[3..5] for col c1
        unsigned short (*hw)[264] = h_lds[(t + 1) & 1];
#pragma unroll
        for (int i = 0; i < 4; ++i) {
            const int r = quad * 4 + i;
            {
                float rg = sigmoid_fast(bf2f(g00[i]) + acc[0][i] + cR0);
                float zg = sigmoid_fast(bf2f(g01[i]) + acc[1][i] + cZ0);
                float ng = tanh_fast(bf2f(g02[i]) + cNi0 + rg * (acc[2][i] + cNh0));
                float hn = zg * (hold0[i] - ng) + ng;
                hold0[i] = hn;
                hw[r][c0] = f2bf(hn);
                if (t == len[i])
                    outp[(size_t)(row0 + r) * 256 + c0] = hn * mask[(row0 + r) * T + t];
            }
            {
                float rg = sigmoid_fast(bf2f(g10[i]) + acc[3][i] + cR1);
                float zg = sigmoid_fast(bf2f(g11[i]) + acc[4][i] + cZ1);
                float ng = tanh_fast(bf2f(g12[i]) + cNi1 + rg * (acc[5][i] + cNh1));
                float hn = zg * (hold1[i] - ng) + ng;
                hold1[i] = hn;
                hw[r][c1] = f2bf(hn);
                if (t == len[i])
                    outp[(size_t)(row0 + r) * 256 + c1] = hn * mask[(row0 + r) * T + t];
            }
        }

        // single barrier: h_{t+1} writes visible; double-buffer removes WAR
        asm volatile("s_waitcnt lgkmcnt(0)" ::: "memory");
        __builtin_amdgcn_sched_barrier(0);
        __builtin_amdgcn_s_barrier();
        __builtin_amdgcn_sched_barrier(0);
    }
}

// Per-batch attention + fc; writes fc_out as bf16; target into d_out tail.
__global__ __launch_bounds__(256) void attn_fc(
    const float* __restrict__ seq_cate, const float* __restrict__ out_short,
    const float* __restrict__ mask_seq, const float* __restrict__ fcWT,
    const float* __restrict__ fc_b, const int* __restrict__ target,
    unsigned short* __restrict__ fc_out, float* __restrict__ d_out)
{
    __shared__ float sc[SUBS][256];
    __shared__ float os[256];
    __shared__ float part[SUBS][256];
    __shared__ float mix[512];
    const int b = blockIdx.x, tid = threadIdx.x;

    os[tid] = out_short[b * 256 + tid];
    for (int s = 0; s < SUBS; ++s) sc[s][tid] = seq_cate[(size_t)(b * SUBS + s) * 256 + tid];
    __syncthreads();

    for (int s = 0; s < SUBS; ++s) part[s][tid] = sc[s][tid] * os[tid];
    __syncthreads();
    for (int off = 128; off >= 1; off >>= 1) {
        if (tid < off)
            for (int s = 0; s < SUBS; ++s) part[s][tid] += part[s][tid + off];
        __syncthreads();
    }

    float w[SUBS];
    float m = -1e30f;
    for (int s = 0; s < SUBS; ++s) m = fmaxf(m, part[s][0]);
    float sum = 0.f;
    for (int s = 0; s < SUBS; ++s) { w[s] = __expf(part[s][0] - m); sum += w[s]; }
    float tot = 0.f;
    for (int s = 0; s < SUBS; ++s) { w[s] = (w[s] / sum) * mask_seq[b * SUBS + s]; tot += w[s]; }
    float inv = 1.f / tot;

    float sumc = 0.f;
    for (int s = 0; s < SUBS; ++s) sumc += w[s] * inv * sc[s][tid];
    mix[tid] = sumc;
    mix[256 + tid] = os[tid];
    __syncthreads();

    float acc = fc_b[tid];
    for (int jj = 0; jj < 512; ++jj) acc = fmaf(mix[jj], fcWT[jj * 256 + tid], acc);
    fc_out[b * 256 + tid] = f2bf(acc);

    if (tid == 0) d_out[(size_t)BATCH * EMB_V + b] = (float)target[b];
}

extern "C" void kernel_launch(void* const* d_in, const int* in_sizes, int n_in,
                              void* d_out, int out_size, void* d_ws, size_t ws_size,
                              hipStream_t stream) {
    const int*   input_cate   = (const int*)d_in[0];
    const float* mask_cate    = (const float*)d_in[1];
    const float* mask_seq     = (const float*)d_in[2];
    const int*   subseqLen    = (const int*)d_in[5];
    const int*   input_batch  = (const int*)d_in[7];
    const float* mask_batch   = (const float*)d_in[8];
    const int*   seqLen_batch = (const int*)d_in[9];
    const int*   target       = (const int*)d_in[10];
    const float* emb          = (const float*)d_in[12];
    const float* Wih_c        = (const float*)d_in[13];
    const float* Whh_c        = (const float*)d_in[14];
    const float* bih_c        = (const float*)d_in[15];
    const float* bhh_c        = (const float*)d_in[16];
    const float* Wih_s        = (const float*)d_in[17];
    const float* Whh_s        = (const float*)d_in[18];
    const float* bih_s        = (const float*)d_in[19];
    const float* bhh_s        = (const float*)d_in[20];
    const float* fc_W         = (const float*)d_in[21];
    const float* fc_b         = (const float*)d_in[22];
    float* out = (float*)d_out;

    float* ws = (float*)d_ws;
    float*          fcWT      = ws;                              // 131072 f
    float*          out_short = ws + 131072;                     // 65536 f
    unsigned short* fc_outb   = (unsigned short*)(ws + 196608);  // 65536 us = 32768 f
    float*          seq_cate  = ws + 229376;                     // 655360 f
    unsigned short* packW_c   = (unsigned short*)(ws + 884736);  // 98304 f
    unsigned short* packW_s   = (unsigned short*)(ws + 983040);  // 98304 f
    unsigned short* wihb_c    = (unsigned short*)(ws + 1081344); // 98304 f
    unsigned short* wihb_s    = (unsigned short*)(ws + 1179648); // 98304 f
    unsigned short* embb      = (unsigned short*)(ws + 1277952); // 12800000 f
    unsigned short* gi_c      = (unsigned short*)(ws + 14077952);// 19660800 f
    unsigned short* gi_s      = (unsigned short*)(ws + 33738752);// 4915200 f

    transpose_rm<<<512, 256, 0, stream>>>(fc_W, fcWT, 256, 512);
    pack_whh<<<96, 256, 0, stream>>>(Whh_c, packW_c);
    pack_whh<<<96, 256, 0, stream>>>(Whh_s, packW_s);

    // one-time bf16 conversions (hoists all staging f2bf out of the GEMMs)
    f32_to_bf16<<<2048, 256, 0, stream>>>(emb, embb, EMB_V * 256 / 4);
    f32_to_bf16<<<192, 256, 0, stream>>>(Wih_c, wihb_c, 768 * 256 / 4);
    f32_to_bf16<<<192, 256, 0, stream>>>(Wih_s, wihb_s, 768 * 256 / 4);

    // input-gate GEMMs: gi = emb[tok] @ Wih^T  (bf16 in, bf16 out)
    gemm_abt<true, true, false><<<dim3(6, 400), 256, 0, stream>>>(
        embb, input_cate, wihb_c, gi_c, 768, 768);
    gemm_abt<true, true, false><<<dim3(6, 100), 256, 0, stream>>>(
        embb, input_batch, wihb_s, gi_s, 768, 768);

    // fused recurrent scans: 160 cat blocks + 16 short blocks, 512 thr
    gru_scan_fused<<<BC / 16 + BATCH / 16, 512, 0, stream>>>(
        gi_c, packW_c, bih_c, bhh_c, subseqLen, mask_cate, seq_cate,
        gi_s, packW_s, bih_s, bhh_s, seqLen_batch, mask_batch, out_short);

    attn_fc<<<BATCH, 256, 0, stream>>>(
        seq_cate, out_short, mask_seq, fcWT, fc_b, target, fc_outb, out);

    // logits = fc_out @ emb^T  (bf16 in, fp32 out)
    gemm_abt<false, false, true><<<dim3(782, 2), 256, 0, stream>>>(
        fc_outb, nullptr, embb, out, EMB_V, EMB_V);
}

// Round 3
// 450.124 us; speedup vs baseline: 1.6343x; 1.0212x over previous
//
#include <hip/hip_runtime.h>
#include <cmath>

#define EMB_V 100000
#define BATCH 256
#define SUBS  10
#define BC    2560
#define TC    20
#define TS    50

using bf16x8 = __attribute__((ext_vector_type(8))) short;
using f32x4  = __attribute__((ext_vector_type(4))) float;

__device__ __forceinline__ unsigned short f2bf(float f) {
    unsigned int u = __float_as_uint(f);
    u += 0x7fff + ((u >> 16) & 1);   // RNE
    return (unsigned short)(u >> 16);
}
__device__ __forceinline__ float bf2f(unsigned short u) {
    return __uint_as_float(((unsigned int)u) << 16);
}
__device__ __forceinline__ float sigmoid_fast(float x) {
    return __builtin_amdgcn_rcpf(1.f + __expf(-x));
}
__device__ __forceinline__ float tanh_fast(float x) {
    float e = __expf(2.f * x);                       // inf-safe: 1 - 2/(e+1)
    return 1.f - 2.f * __builtin_amdgcn_rcpf(e + 1.f);
}
// async 16B global -> LDS DMA. dst must be wave-uniform; HW adds lane*16.
__device__ __forceinline__ void dma16(const void* g, void* l) {
    __builtin_amdgcn_global_load_lds((const __attribute__((address_space(1))) void*)g,
                                     (__attribute__((address_space(3))) void*)l, 16, 0, 0);
}

// ---- merged small prep: fcWT transpose, pack_whh x2, Wih bf16 conv x2 ----
__device__ __forceinline__ void pack_whh_dev(const float* __restrict__ W,
                                             unsigned short* __restrict__ P, int t) {
    if (t >= 48 * 8 * 64) return;
    int l = t & 63, kc = (t >> 6) & 7, nt = t >> 9;
    int g = nt % 3, cg = nt / 3;
    int n = g * 256 + cg * 16 + (l & 15);
    int k = kc * 32 + (l >> 4) * 8;
    const float* src = W + n * 256 + k;
    unsigned short* dst = P + (size_t)t * 8;
#pragma unroll
    for (int j = 0; j < 8; ++j) dst[j] = f2bf(src[j]);
}
__global__ __launch_bounds__(256) void prep_misc(
    const float* __restrict__ fc_W, float* __restrict__ fcWT,
    const float* __restrict__ Whh_c, unsigned short* __restrict__ packW_c,
    const float* __restrict__ Whh_s, unsigned short* __restrict__ packW_s,
    const float* __restrict__ Wih_c, unsigned short* __restrict__ wihb_c,
    const float* __restrict__ Wih_s, unsigned short* __restrict__ wihb_s)
{
    const int b = blockIdx.x, tid = threadIdx.x;
    if (b < 512) {                       // fcWT[c*256+r] = fc_W[r*512+c]
        int o = b * 256 + tid;
        int c = o >> 8, r = o & 255;
        fcWT[o] = fc_W[r * 512 + c];
    } else if (b < 608) {
        pack_whh_dev(Whh_c, packW_c, (b - 512) * 256 + tid);
    } else if (b < 704) {
        pack_whh_dev(Whh_s, packW_s, (b - 608) * 256 + tid);
    } else if (b < 896) {
        int i = (b - 704) * 256 + tid;   // 49152 float4's
        float4 v = ((const float4*)Wih_c)[i];
        ((ushort4*)wihb_c)[i] = make_ushort4(f2bf(v.x), f2bf(v.y), f2bf(v.z), f2bf(v.w));
    } else {
        int i = (b - 896) * 256 + tid;
        float4 v = ((const float4*)Wih_s)[i];
        ((ushort4*)wihb_s)[i] = make_ushort4(f2bf(v.x), f2bf(v.y), f2bf(v.z), f2bf(v.w));
    }
}

// fp32 -> bf16 (RNE), vectorized, grid-strided. n4 = n/4.
__global__ void f32_to_bf16(const float* __restrict__ in, unsigned short* __restrict__ out,
                            int n4) {
    for (int i = blockIdx.x * 256 + threadIdx.x; i < n4; i += gridDim.x * 256) {
        float4 v = ((const float4*)in)[i];
        ((ushort4*)out)[i] = make_ushort4(f2bf(v.x), f2bf(v.y), f2bf(v.z), f2bf(v.w));
    }
}

// Generic C[m][n] = sum_k A[m][k]*B[n][k], K=256, BM=BN=128, bf16 inputs.
// m97-style staging: global_load_lds width-16 direct to linear [128][64] LDS.
// Frag reads eat the 16-way conflict (T2 null at 2-phase per regime gate).
template <bool GATHER, bool OBF16, bool NGUARD>
__global__ __launch_bounds__(256, 3) void gemm_abt(
    const unsigned short* __restrict__ A, const int* __restrict__ tok,
    const unsigned short* __restrict__ B, void* __restrict__ Cout,
    int N, int ldc)
{
    __shared__ unsigned short Asub[128 * 64];
    __shared__ unsigned short Bsub[128 * 64];
    const int tid = threadIdx.x;
    const int l = tid & 63, wave = tid >> 6;
    const int lm = l & 15, quad = l >> 4;
    const int wm = wave >> 1, wn = wave & 1;
    const int n0 = blockIdx.x * 128, m0 = blockIdx.y * 128;

    // per-thread source offsets (u16 elements) for the 4 DMA issues of each tile
    unsigned aofs[4], bofs[4];
#pragma unroll
    for (int i = 0; i < 4; ++i) {
        int c = tid + i * 256, row = c >> 3, cc = c & 7;
        aofs[i] = (GATHER ? (unsigned)tok[m0 + row] : (unsigned)(m0 + row)) * 256u + cc * 8u;
        // NGUARD: OOB rows read adjacent workspace garbage; their cols are skipped at C-write.
        bofs[i] = (unsigned)(n0 + row) * 256u + cc * 8u;
    }
    const int dstu = (tid & 192) * 8;    // wave-uniform chunk base (u16)

    f32x4 acc[4][4];
#pragma unroll
    for (int mi = 0; mi < 4; ++mi)
#pragma unroll
        for (int ni = 0; ni < 4; ++ni) acc[mi][ni] = (f32x4){0.f, 0.f, 0.f, 0.f};

    for (int kk = 0; kk < 4; ++kk) {
        const int k0 = kk * 64;
#pragma unroll
        for (int i = 0; i < 4; ++i)
            dma16(A + aofs[i] + k0, &Asub[dstu + i * 2048]);
#pragma unroll
        for (int i = 0; i < 4; ++i)
            dma16(B + bofs[i] + k0, &Bsub[dstu + i * 2048]);
        __syncthreads();   // vmcnt(0) drain -> DMA complete
#pragma unroll
        for (int kc = 0; kc < 2; ++kc) {
            bf16x8 af[4], bfv[4];
#pragma unroll
            for (int mi = 0; mi < 4; ++mi)
                af[mi] = *(const bf16x8*)&Asub[(wm * 64 + mi * 16 + lm) * 64 + kc * 32 + quad * 8];
#pragma unroll
            for (int ni = 0; ni < 4; ++ni)
                bfv[ni] = *(const bf16x8*)&Bsub[(wn * 64 + ni * 16 + lm) * 64 + kc * 32 + quad * 8];
#pragma unroll
            for (int mi = 0; mi < 4; ++mi)
#pragma unroll
                for (int ni = 0; ni < 4; ++ni)
                    acc[mi][ni] = __builtin_amdgcn_mfma_f32_16x16x32_bf16(
                        af[mi], bfv[ni], acc[mi][ni], 0, 0, 0);
        }
        __syncthreads();
    }
#pragma unroll
    for (int mi = 0; mi < 4; ++mi)
#pragma unroll
        for (int ni = 0; ni < 4; ++ni) {
            int col = n0 + wn * 64 + ni * 16 + lm;
            if (NGUARD && col >= N) continue;
#pragma unroll
            for (int i = 0; i < 4; ++i) {
                int row = m0 + wm * 64 + mi * 16 + quad * 4 + i;
                if (OBF16)
                    ((unsigned short*)Cout)[(size_t)row * ldc + col] = f2bf(acc[mi][ni][i]);
                else
                    ((float*)Cout)[(size_t)row * ldc + col] = acc[mi][ni][i];
            }
        }
}

// Fused GRU scans (cat: blocks 0..159, T=20; short: 160..175, T=50).
// 512 thr = 8 waves, 16 rows/block. B-frags: 44 in regs, 4 in LDS.
// gi staged via global_load_lds, double-buffered one step ahead (HBM latency
// fully hidden). Gates in-lane from accumulators (gate-triple-interleaved W).
// h double-buffered bf16 in LDS; one raw barrier/step with vmcnt+lgkm drain.
__global__ __launch_bounds__(512, 2) void gru_scan_fused(
    const unsigned short* __restrict__ gi_c, const unsigned short* __restrict__ pW_c,
    const float* __restrict__ bih_c, const float* __restrict__ bhh_c,
    const int* __restrict__ len_c, const float* __restrict__ mask_c,
    float* __restrict__ out_c,
    const unsigned short* __restrict__ gi_s, const unsigned short* __restrict__ pW_s,
    const float* __restrict__ bih_s, const float* __restrict__ bhh_s,
    const int* __restrict__ len_s, const float* __restrict__ mask_s,
    float* __restrict__ out_s)
{
    __shared__ unsigned short h_lds[2][16][264];   // 16896 B
    __shared__ unsigned short b_lds[8 * 4 * 512];  // 32768 B (4 frags/wave)
    __shared__ unsigned short gi_lds[2][16 * 768]; // 49152 B (linear, DMA dst)

    const bool is_cat = blockIdx.x < (BC / 16);
    const int  T      = is_cat ? TC : TS;
    const int  row0   = (is_cat ? blockIdx.x : blockIdx.x - BC / 16) * 16;
    const unsigned short* gi   = is_cat ? gi_c  : gi_s;
    const unsigned short* pW   = is_cat ? pW_c  : pW_s;
    const float*          bih  = is_cat ? bih_c : bih_s;
    const float*          bhh  = is_cat ? bhh_c : bhh_s;
    const int*            lenp = is_cat ? len_c : len_s;
    const float*          mask = is_cat ? mask_c : mask_s;
    float*                outp = is_cat ? out_c : out_s;

    const int tid  = threadIdx.x;
    const int l    = tid & 63, w = tid >> 6;
    const int lm   = l & 15,   quad = l >> 4;

    // zero both h buffers
    for (int i = tid; i < 2 * 16 * 264; i += 512) ((unsigned short*)h_lds)[i] = 0;

    // B frags: reg idx = ti*8+kc (ti<5) | 40+kc (ti==5,kc<4); rest to LDS
    bf16x8 breg[44];
#pragma unroll
    for (int ti = 0; ti < 6; ++ti)
#pragma unroll
        for (int kc = 0; kc < 8; ++kc) {
            bf16x8 v = *((const bf16x8*)pW + (size_t)((6 * w + ti) * 8 + kc) * 64 + l);
            if (ti < 5)           breg[ti * 8 + kc] = v;
            else if (kc < 4)      breg[40 + kc] = v;
            else *(bf16x8*)&b_lds[((w * 4 + (kc - 4)) * 64 + l) * 8] = v;
        }

    // per-lane columns and bias constants
    const int c0 = 32 * w + lm, c1 = c0 + 16;
    const float cR0 = bih[c0] + bhh[c0],             cR1 = bih[c1] + bhh[c1];
    const float cZ0 = bih[256 + c0] + bhh[256 + c0], cZ1 = bih[256 + c1] + bhh[256 + c1];
    const float cNi0 = bih[512 + c0], cNi1 = bih[512 + c1];
    const float cNh0 = bhh[512 + c0], cNh1 = bhh[512 + c1];

    int len[4];
#pragma unroll
    for (int i = 0; i < 4; ++i) len[i] = lenp[row0 + quad * 4 + i];

    // gi DMA: 3 issues/thread; chunk c = w*64 + l + i*512; row = c/96, cc = c%96
    const unsigned short* gq[3];
    const int dstu = (tid & 448) * 8;    // wave-uniform u16 base; HW adds lane*16
#pragma unroll
    for (int i = 0; i < 3; ++i) {
        int c = tid + i * 512;
        int row = c / 96, cc = c - row * 96;
        gq[i] = gi + ((size_t)(row0 + row) * T) * 768 + cc * 8;
    }
    // prologue: stage t=0 into buf0
#pragma unroll
    for (int i = 0; i < 3; ++i) {
        dma16(gq[i], &gi_lds[0][dstu + i * 8192]);
        gq[i] += 768;   // now points at t=1
    }

    float hold0[4] = {0.f, 0.f, 0.f, 0.f};
    float hold1[4] = {0.f, 0.f, 0.f, 0.f};

    __syncthreads();   // drains vmcnt (gi t=0) + lgkm (h zero, b_lds)

    for (int t = 0; t < T; ++t) {
        // stage gi for t+1 into the other buffer (hidden under this step)
        if (t + 1 < T) {
#pragma unroll
            for (int i = 0; i < 3; ++i) {
                dma16(gq[i], &gi_lds[(t + 1) & 1][dstu + i * 8192]);
                gq[i] += 768;
            }
        }

        // gh = h @ WhhT, kc-outer (1 live A-frag), acc[ti] spacing = 6 MFMAs
        const unsigned short (*hb)[264] = h_lds[t & 1];
        f32x4 acc[6];
#pragma unroll
        for (int ti = 0; ti < 6; ++ti) acc[ti] = (f32x4){0.f, 0.f, 0.f, 0.f};
#pragma unroll
        for (int kc = 0; kc < 8; ++kc) {
            bf16x8 a = *(const bf16x8*)&hb[lm][kc * 32 + quad * 8];
#pragma unroll
            for (int ti = 0; ti < 6; ++ti) {
                bf16x8 b;
                if (ti < 5)           b = breg[ti * 8 + kc];
                else if (kc < 4)      b = breg[40 + kc];
                else b = *(const bf16x8*)&b_lds[((w * 4 + (kc - 4)) * 64 + l) * 8];
                acc[ti] = __builtin_amdgcn_mfma_f32_16x16x32_bf16(a, b, acc[ti], 0, 0, 0);
            }
        }

        // gates: gi from LDS (this step's buffer), acc in-lane
        const unsigned short* gb = gi_lds[t & 1];
        unsigned short (*hw)[264] = h_lds[(t + 1) & 1];
#pragma unroll
        for (int i = 0; i < 4; ++i) {
            const int r = quad * 4 + i;
            const unsigned short* gr = gb + r * 768;
            {
                float rg = sigmoid_fast(bf2f(gr[c0]) + acc[0][i] + cR0);
                float zg = sigmoid_fast(bf2f(gr[256 + c0]) + acc[1][i] + cZ0);
                float ng = tanh_fast(bf2f(gr[512 + c0]) + cNi0 + rg * (acc[2][i] + cNh0));
                float hn = zg * (hold0[i] - ng) + ng;
                hold0[i] = hn;
                hw[r][c0] = f2bf(hn);
                if (t == len[i])
                    outp[(size_t)(row0 + r) * 256 + c0] = hn * mask[(row0 + r) * T + t];
            }
            {
                float rg = sigmoid_fast(bf2f(gr[c1]) + acc[3][i] + cR1);
                float zg = sigmoid_fast(bf2f(gr[256 + c1]) + acc[4][i] + cZ1);
                float ng = tanh_fast(bf2f(gr[512 + c1]) + cNi1 + rg * (acc[5][i] + cNh1));
                float hn = zg * (hold1[i] - ng) + ng;
                hold1[i] = hn;
                hw[r][c1] = f2bf(hn);
                if (t == len[i])
                    outp[(size_t)(row0 + r) * 256 + c1] = hn * mask[(row0 + r) * T + t];
            }
        }

        // one barrier/step: h writes + next-step gi DMA must be complete
        asm volatile("s_waitcnt vmcnt(0) lgkmcnt(0)" ::: "memory");
        __builtin_amdgcn_sched_barrier(0);
        __builtin_amdgcn_s_barrier();
        __builtin_amdgcn_sched_barrier(0);
    }
}

// Per-batch attention + fc; writes fc_out as bf16; target into d_out tail.
__global__ __launch_bounds__(256) void attn_fc(
    const float* __restrict__ seq_cate, const float* __restrict__ out_short,
    const float* __restrict__ mask_seq, const float* __restrict__ fcWT,
    const float* __restrict__ fc_b, const int* __restrict__ target,
    unsigned short* __restrict__ fc_out, float* __restrict__ d_out)
{
    __shared__ float sc[SUBS][256];
    __shared__ float os[256];
    __shared__ float part[SUBS][256];
    __shared__ float mix[512];
    const int b = blockIdx.x, tid = threadIdx.x;

    os[tid] = out_short[b * 256 + tid];
    for (int s = 0; s < SUBS; ++s) sc[s][tid] = seq_cate[(size_t)(b * SUBS + s) * 256 + tid];
    __syncthreads();

    for (int s = 0; s < SUBS; ++s) part[s][tid] = sc[s][tid] * os[tid];
    __syncthreads();
    for (int off = 128; off >= 1; off >>= 1) {
        if (tid < off)
            for (int s = 0; s < SUBS; ++s) part[s][tid] += part[s][tid + off];
        __syncthreads();
    }

    float w[SUBS];
    float m = -1e30f;
    for (int s = 0; s < SUBS; ++s) m = fmaxf(m, part[s][0]);
    float sum = 0.f;
    for (int s = 0; s < SUBS; ++s) { w[s] = __expf(part[s][0] - m); sum += w[s]; }
    float tot = 0.f;
    for (int s = 0; s < SUBS; ++s) { w[s] = (w[s] / sum) * mask_seq[b * SUBS + s]; tot += w[s]; }
    float inv = 1.f / tot;

    float sumc = 0.f;
    for (int s = 0; s < SUBS; ++s) sumc += w[s] * inv * sc[s][tid];
    mix[tid] = sumc;
    mix[256 + tid] = os[tid];
    __syncthreads();

    float acc = fc_b[tid];
    for (int jj = 0; jj < 512; ++jj) acc = fmaf(mix[jj], fcWT[jj * 256 + tid], acc);
    fc_out[b * 256 + tid] = f2bf(acc);

    if (tid == 0) d_out[(size_t)BATCH * EMB_V + b] = (float)target[b];
}

extern "C" void kernel_launch(void* const* d_in, const int* in_sizes, int n_in,
                              void* d_out, int out_size, void* d_ws, size_t ws_size,
                              hipStream_t stream) {
    const int*   input_cate   = (const int*)d_in[0];
    const float* mask_cate    = (const float*)d_in[1];
    const float* mask_seq     = (const float*)d_in[2];
    const int*   subseqLen    = (const int*)d_in[5];
    const int*   input_batch  = (const int*)d_in[7];
    const float* mask_batch   = (const float*)d_in[8];
    const int*   seqLen_batch = (const int*)d_in[9];
    const int*   target       = (const int*)d_in[10];
    const float* emb          = (const float*)d_in[12];
    const float* Wih_c        = (const float*)d_in[13];
    const float* Whh_c        = (const float*)d_in[14];
    const float* bih_c        = (const float*)d_in[15];
    const float* bhh_c        = (const float*)d_in[16];
    const float* Wih_s        = (const float*)d_in[17];
    const float* Whh_s        = (const float*)d_in[18];
    const float* bih_s        = (const float*)d_in[19];
    const float* bhh_s        = (const float*)d_in[20];
    const float* fc_W         = (const float*)d_in[21];
    const float* fc_b         = (const float*)d_in[22];
    float* out = (float*)d_out;

    float* ws = (float*)d_ws;
    float*          fcWT      = ws;                              // 131072 f
    float*          out_short = ws + 131072;                     // 65536 f
    unsigned short* fc_outb   = (unsigned short*)(ws + 196608);  // 65536 us
    float*          seq_cate  = ws + 229376;                     // 655360 f
    unsigned short* packW_c   = (unsigned short*)(ws + 884736);  // 98304 f
    unsigned short* packW_s   = (unsigned short*)(ws + 983040);  // 98304 f
    unsigned short* wihb_c    = (unsigned short*)(ws + 1081344); // 98304 f
    unsigned short* wihb_s    = (unsigned short*)(ws + 1179648); // 98304 f
    unsigned short* embb      = (unsigned short*)(ws + 1277952); // 12800000 f
    unsigned short* gi_c      = (unsigned short*)(ws + 14077952);// 19660800 f
    unsigned short* gi_s      = (unsigned short*)(ws + 33738752);// 4915200 f

    prep_misc<<<1088, 256, 0, stream>>>(fc_W, fcWT, Whh_c, packW_c, Whh_s, packW_s,
                                        Wih_c, wihb_c, Wih_s, wihb_s);
    f32_to_bf16<<<2048, 256, 0, stream>>>(emb, embb, EMB_V * 256 / 4);

    // input-gate GEMMs: gi = emb[tok] @ Wih^T  (bf16 in, bf16 out)
    gemm_abt<true, true, false><<<dim3(6, 400), 256, 0, stream>>>(
        embb, input_cate, wihb_c, gi_c, 768, 768);
    gemm_abt<true, true, false><<<dim3(6, 100), 256, 0, stream>>>(
        embb, input_batch, wihb_s, gi_s, 768, 768);

    // fused recurrent scans: 160 cat blocks + 16 short blocks, 512 thr
    gru_scan_fused<<<BC / 16 + BATCH / 16, 512, 0, stream>>>(
        gi_c, packW_c, bih_c, bhh_c, subseqLen, mask_cate, seq_cate,
        gi_s, packW_s, bih_s, bhh_s, seqLen_batch, mask_batch, out_short);

    attn_fc<<<BATCH, 256, 0, stream>>>(
        seq_cate, out_short, mask_seq, fcWT, fc_b, target, fc_outb, out);

    // logits = fc_out @ emb^T  (bf16 in, fp32 out)
    gemm_abt<false, false, true><<<dim3(782, 2), 256, 0, stream>>>(
        fc_outb, nullptr, embb, out, EMB_V, EMB_V);
}